// Round 3
// baseline (237.568 us; speedup 1.0000x reference)
//
#include <hip/hip_runtime.h>
#include <hip/hip_bf16.h>

// out[b] = ||xd_b||^2 - (s_b . xd_b)^2 / (1 + ||s_b||^2), s = x @ W^T.
// bf16 MFMA GEMM, 256x256 tile, BK=64, 8-phase schedule (T2 swizzle + T3/T4
// counted vmcnt + T5 setprio), fused reduction epilogue. s never materialized.
// R3: builtin s_barrier (no "memory" clobber -> no forced vmcnt drain; the
// R2 asm-with-clobber barriers silently degraded to drain-0 = m218-V1);
// persistent blocks: grid=256, 2 tiles/block (same brow, two bcols), one
// continuous staging pipeline across the seam; epilogue-0 overlapped with
// tile-1 staging.

#define MTOT 16384
#define DTOT 2048
#define NT_FLAT 64   // 2 tiles x 32 K-steps of BK=64

typedef unsigned short u16;
typedef __attribute__((ext_vector_type(4))) float f32x4;
typedef __attribute__((ext_vector_type(8))) short bf16x8;
typedef __attribute__((ext_vector_type(8))) unsigned short u16x8;

__device__ __forceinline__ u16 f2bf(float f) {
    union { float f; unsigned int u; } v; v.f = f;
    unsigned int u = v.u;
    u += 0x7fffu + ((u >> 16) & 1u);   // RNE (inputs finite)
    return (u16)(u >> 16);
}

__device__ __forceinline__ void gload_lds16(const void* gptr, void* ldsptr) {
    __builtin_amdgcn_global_load_lds(
        (const __attribute__((address_space(1))) unsigned int*)gptr,
        (__attribute__((address_space(3))) unsigned int*)ldsptr,
        16, 0, 0);
}

#define BARS()   __builtin_amdgcn_s_barrier()
#define LGKM0()  asm volatile("s_waitcnt lgkmcnt(0)")
#define WAITV(n) asm volatile("s_waitcnt vmcnt(" #n ")")

// ---------------- cast f32 -> bf16 ----------------
__global__ void cast_kernel(const float* __restrict__ src, u16* __restrict__ dst, int n8) {
    int stride = gridDim.x * blockDim.x;
    for (int i = blockIdx.x * blockDim.x + threadIdx.x; i < n8; i += stride) {
        f32x4 a = ((const f32x4*)src)[2 * (size_t)i];
        f32x4 b = ((const f32x4*)src)[2 * (size_t)i + 1];
        u16x8 r;
        r[0] = f2bf(a[0]); r[1] = f2bf(a[1]); r[2] = f2bf(a[2]); r[3] = f2bf(a[3]);
        r[4] = f2bf(b[0]); r[5] = f2bf(b[1]); r[6] = f2bf(b[2]); r[7] = f2bf(b[3]);
        ((u16x8*)dst)[i] = r;
    }
}

// ---------------- 8-phase 256^2 GEMM + fused reductions ----------------
// grid = 256 blocks x 512 threads (8 waves, 2M x 4N). Block bid: colpair
// c=(bid&7)>>1 -> bcol0=c*512, bcol1=bcol0+256; brow=((bid>>3)*2+(bid&1))*256.
// XCD k (=bid%8) sees only W cols [c*512, c*512+512) -> 2 MB, L2-resident.
// Flat K-tile index u in [0,64): u<32 -> (brow,bcol0), u>=32 -> (brow,bcol1);
// staging pipeline runs continuously across the seam (no drain, no re-prologue).
// Per K-tile, 4 phases x {ds_read subtile; stage half-tile; s_barrier;
// lgkmcnt(0); setprio(1); 16 MFMA; setprio(0); s_barrier}; vmcnt(6) only at
// the tile boundary (3 half-tiles = 6 loads stay in flight).
__global__ __launch_bounds__(512, 2)
void gemm8(const u16* __restrict__ xbf, const u16* __restrict__ wbf,
           const float* __restrict__ xdot,
           float* __restrict__ ns_acc, float* __restrict__ sx_acc,
           float* __restrict__ xx_acc) {
    __shared__ u16 lds[65536];   // 128 KiB: [2 buf][A0,A1,B0,B1 x 16 KiB]

    const int tid  = threadIdx.x;
    const int lane = tid & 63;
    const int wid  = tid >> 6;
    const int wr = wid >> 2, wc = wid & 3;     // 2 x 4 wave grid
    const int fr = lane & 15, fq = lane >> 4;

    const int bid   = blockIdx.x;              // 256
    const int cpair = (bid & 7) >> 1;
    const int brow  = ((bid >> 3) * 2 + (bid & 1)) * 256;
    const int bcol0 = cpair * 512;
    const int bcol1 = bcol0 + 256;

    // per-thread staging offsets: thread covers rows i>>3, 16B slot i&7, for
    // i = tid and 512+tid. Swizzle: global slot ^= (row&7); LDS dest linear.
    const int i0 = tid, i1 = 512 + tid;
    const int r0 = i0 >> 3, sl0 = i0 & 7;
    const int r1 = i1 >> 3, sl1 = i1 & 7;
    const size_t poff0 = (size_t)r0 * DTOT + ((sl0 ^ (r0 & 7)) << 3);
    const size_t poff1 = (size_t)r1 * DTOT + ((sl1 ^ (r1 & 7)) << 3);

    auto stage2 = [&](const u16* base, int ldsbyte) {
        gload_lds16(base + poff0, (char*)lds + ldsbyte + i0 * 16);
        gload_lds16(base + poff1, (char*)lds + ldsbyte + i1 * 16);
    };
    auto stA = [&](int v, int half, int ldsbyte) {      // A half-tile of flat-tile v
        v = v > NT_FLAT - 1 ? NT_FLAT - 1 : v;
        stage2(xbf + (size_t)(brow + half * 128) * DTOT + (size_t)((v & 31) * 64), ldsbyte);
    };
    auto stB = [&](int v, int half, int ldsbyte) {      // B half-tile of flat-tile v
        v = v > NT_FLAT - 1 ? NT_FLAT - 1 : v;
        const int cb = (v < 32 ? bcol0 : bcol1) + half * 128;
        stage2(wbf + (size_t)cb * DTOT + (size_t)((v & 31) * 64), ldsbyte);
    };

    // swizzled fragment read (u16-unit index): logical slot s -> physical s^(row&7)
#define FRAG(base_u16, row, s) \
    (*(const bf16x8*)&lds[(base_u16) + (row) * 64 + (((s) ^ ((row) & 7)) << 3)])

    f32x4 acc[8][4] = {};
    bf16x8 Af[2][4], Bf[2][4];

    auto epilogue = [&](int bcol_e) {
        // C/D layout col = lane&15, row = (lane>>4)*4 + reg (m89-verified).
#pragma unroll
        for (int m = 0; m < 8; ++m) {
#pragma unroll
            for (int jj = 0; jj < 4; ++jj) {
                const int row = brow + wr * 128 + m * 16 + fq * 4 + jj;
                const float* xp = xdot + (size_t)row * DTOT + bcol_e + wc * 64 + fr;
                float pns = 0.f, psx = 0.f, pxx = 0.f;
#pragma unroll
                for (int n = 0; n < 4; ++n) {
                    float s  = acc[m][n][jj];
                    float xv = xp[n * 16];
                    pns += s * s; psx += s * xv; pxx += xv * xv;
                }
#pragma unroll
                for (int msk = 1; msk < 16; msk <<= 1) {
                    pns += __shfl_xor(pns, msk);
                    psx += __shfl_xor(psx, msk);
                    pxx += __shfl_xor(pxx, msk);
                }
                if (fr == 0) {
                    atomicAdd(&ns_acc[row], pns);
                    atomicAdd(&sx_acc[row], psx);
                    atomicAdd(&xx_acc[row], pxx);
                }
            }
        }
    };

    // ---- prologue: flat-tile 0 fully + tile 1 {B0,B1,A0}
    stA(0, 0, 0);             stA(0, 1, 16384);
    stB(0, 0, 32768);         stB(0, 1, 49152);
    stB(1, 0, 65536 + 32768); stB(1, 1, 65536 + 49152);
    stA(1, 0, 65536 + 0);
    WAITV(6);   // tile 0's 8 loads landed; tile 1's 6 may fly
    BARS();

    auto kloop = [&](int u0) {
        for (int t = 0; t < 32; ++t) {
            const int u = u0 + t;
            const int cur   = u & 1;
            const int abase = cur * 32768 + wr * 8192;                 // u16 units
            const int bbase = cur * 32768 + 16384 + (wc >> 1) * 8192;
            const int brB   = (wc & 1) * 64;
            const int bufn  = (cur ^ 1) * 65536;   // buf of tile u+1
            const int bufc  = cur * 65536;         // buf of tile u+2 (freed regions)

            // ---- P0: read A[m0-3]+B[n0-1]; stage (u+1).A1
#pragma unroll
            for (int ks = 0; ks < 2; ++ks) {
#pragma unroll
                for (int m = 0; m < 4; ++m) Af[ks][m] = FRAG(abase, m * 16 + fr, ks * 4 + fq);
#pragma unroll
                for (int n = 0; n < 2; ++n) Bf[ks][n] = FRAG(bbase, brB + n * 16 + fr, ks * 4 + fq);
            }
            stA(u + 1, 1, bufn + 16384);
            BARS(); LGKM0();
            __builtin_amdgcn_s_setprio(1);
#pragma unroll
            for (int m = 0; m < 4; ++m)
#pragma unroll
                for (int n = 0; n < 2; ++n)
#pragma unroll
                    for (int ks = 0; ks < 2; ++ks)
                        acc[m][n] = __builtin_amdgcn_mfma_f32_16x16x32_bf16(Af[ks][m], Bf[ks][n], acc[m][n], 0, 0, 0);
            __builtin_amdgcn_s_setprio(0);
            BARS();

            // ---- P1: read B[n2-3]; MFMA m0-3 x n2-3 (B region dead after)
#pragma unroll
            for (int ks = 0; ks < 2; ++ks)
#pragma unroll
                for (int n = 0; n < 2; ++n) Bf[ks][2 + n] = FRAG(bbase, brB + (2 + n) * 16 + fr, ks * 4 + fq);
            BARS(); LGKM0();
            __builtin_amdgcn_s_setprio(1);
#pragma unroll
            for (int m = 0; m < 4; ++m)
#pragma unroll
                for (int n = 0; n < 2; ++n)
#pragma unroll
                    for (int ks = 0; ks < 2; ++ks)
                        acc[m][2 + n] = __builtin_amdgcn_mfma_f32_16x16x32_bf16(Af[ks][m], Bf[ks][2 + n], acc[m][2 + n], 0, 0, 0);
            __builtin_amdgcn_s_setprio(0);
            BARS();

            // ---- P2: read A[m4-7]; stage (u+2).B0 into freed B region
#pragma unroll
            for (int ks = 0; ks < 2; ++ks)
#pragma unroll
                for (int m = 0; m < 4; ++m) Af[ks][m] = FRAG(abase, 64 + m * 16 + fr, ks * 4 + fq);
            stB(u + 2, 0, bufc + 32768);
            BARS(); LGKM0();
            __builtin_amdgcn_s_setprio(1);
#pragma unroll
            for (int m = 0; m < 4; ++m)
#pragma unroll
                for (int n = 0; n < 2; ++n)
#pragma unroll
                    for (int ks = 0; ks < 2; ++ks)
                        acc[4 + m][2 + n] = __builtin_amdgcn_mfma_f32_16x16x32_bf16(Af[ks][m], Bf[ks][2 + n], acc[4 + m][2 + n], 0, 0, 0);
            __builtin_amdgcn_s_setprio(0);
            BARS();

            // ---- P3: stage (u+2).B1 + (u+2).A0 (A freed at P2 barrier); MFMA m4-7 x n0-1
            stB(u + 2, 1, bufc + 49152);
            stA(u + 2, 0, bufc + 0);
            BARS(); LGKM0();
            __builtin_amdgcn_s_setprio(1);
#pragma unroll
            for (int m = 0; m < 4; ++m)
#pragma unroll
                for (int n = 0; n < 2; ++n)
#pragma unroll
                    for (int ks = 0; ks < 2; ++ks)
                        acc[4 + m][n] = __builtin_amdgcn_mfma_f32_16x16x32_bf16(Af[ks][m], Bf[ks][n], acc[4 + m][n], 0, 0, 0);
            __builtin_amdgcn_s_setprio(0);
            // boundary: 8 issued this iter; wait so only (u+2)'s 6 remain in flight
            WAITV(6);
            BARS();
        }
    };

    kloop(0);
    // tile-0 epilogue overlaps with tile-1's in-flight stages (no LDS use here)
    epilogue(bcol0);
#pragma unroll
    for (int m = 0; m < 8; ++m)
#pragma unroll
        for (int n = 0; n < 4; ++n)
#pragma unroll
            for (int k = 0; k < 4; ++k) acc[m][n][k] = 0.f;
    WAITV(0);   // drain epilogue atomics + pending stages -> invariant restored
    BARS();
    kloop(32);
    WAITV(0);   // drain clamped tail stages before epilogue/exit
    BARS();
    epilogue(bcol1);
#undef FRAG
}

__global__ void finalize_k(const float* __restrict__ ns, const float* __restrict__ sx,
                           const float* __restrict__ xx, float* __restrict__ out) {
    int i = blockIdx.x * blockDim.x + threadIdx.x;
    if (i < MTOT) out[i] = xx[i] - (sx[i] * sx[i]) / (1.0f + ns[i]);
}

extern "C" void kernel_launch(void* const* d_in, const int* in_sizes, int n_in,
                              void* d_out, int out_size, void* d_ws, size_t ws_size,
                              hipStream_t stream) {
    const float* x  = (const float*)d_in[0];
    const float* xd = (const float*)d_in[1];
    const float* W  = (const float*)d_in[2];
    float* out = (float*)d_out;

    const size_t xbf_bytes = (size_t)MTOT * DTOT * 2;   // 67.1 MB
    const size_t wbf_bytes = (size_t)DTOT * DTOT * 2;   //  8.4 MB
    const size_t acc_bytes = (size_t)3 * MTOT * 4;      //  0.2 MB

    u16* xbf = (u16*)d_ws;
    u16* wbf = (u16*)((char*)d_ws + xbf_bytes);
    float* accs = (float*)((char*)d_ws + xbf_bytes + wbf_bytes);
    float* nsA = accs;
    float* sxA = accs + MTOT;
    float* xxA = accs + 2 * MTOT;
    (void)ws_size; (void)in_sizes; (void)n_in; (void)out_size;

    hipMemsetAsync(accs, 0, acc_bytes, stream);  // re-zero every call

    cast_kernel<<<2048, 256, 0, stream>>>(x, xbf, MTOT * DTOT / 8);
    cast_kernel<<<512, 256, 0, stream>>>(W, wbf, DTOT * DTOT / 8);
    gemm8<<<256, 512, 0, stream>>>(xbf, wbf, xd, nsA, sxA, xxA);
    finalize_k<<<MTOT / 256, 256, 0, stream>>>(nsA, sxA, xxA, out);
}

// Round 4
// 205.883 us; speedup vs baseline: 1.1539x; 1.1539x over previous
//
#include <hip/hip_runtime.h>
#include <hip/hip_bf16.h>

// out[b] = ||xd_b||^2 - (s_b . xd_b)^2 / (1 + ||s_b||^2), s = x @ W^T.
// bf16 MFMA GEMM, 256x256 tile, BK=64, 8-phase schedule (T2 swizzle + T3/T4
// counted vmcnt + T5 setprio), fused reduction epilogue. s never materialized.
// R4: R2's grid/tile/XCD structure (512 blocks, 1 tile/block, W panel per XCD)
// + m201 sync primitives: raw builtin s_barrier (no "memory" clobber -> no
// forced vmcnt drain; R2's clobbered asm barriers silently degraded the
// schedule to drain-0 = m218-V1), lgkmcnt(0) after the pre-MFMA barrier,
// vmcnt(6) only at the K-tile boundary, clamped tail stages (idempotent).

#define MTOT 16384
#define DTOT 2048
#define NTILES 32   // DTOT / 64

typedef unsigned short u16;
typedef __attribute__((ext_vector_type(4))) float f32x4;
typedef __attribute__((ext_vector_type(8))) short bf16x8;
typedef __attribute__((ext_vector_type(8))) unsigned short u16x8;

__device__ __forceinline__ u16 f2bf(float f) {
    union { float f; unsigned int u; } v; v.f = f;
    unsigned int u = v.u;
    u += 0x7fffu + ((u >> 16) & 1u);   // RNE (inputs finite)
    return (u16)(u >> 16);
}

__device__ __forceinline__ void gload_lds16(const void* gptr, void* ldsptr) {
    __builtin_amdgcn_global_load_lds(
        (const __attribute__((address_space(1))) unsigned int*)gptr,
        (__attribute__((address_space(3))) unsigned int*)ldsptr,
        16, 0, 0);
}

#define BARS()   __builtin_amdgcn_s_barrier()
#define LGKM0()  asm volatile("s_waitcnt lgkmcnt(0)")
#define WAITV(n) asm volatile("s_waitcnt vmcnt(" #n ")")

// ---------------- cast f32 -> bf16 ----------------
__global__ void cast_kernel(const float* __restrict__ src, u16* __restrict__ dst, int n8) {
    int stride = gridDim.x * blockDim.x;
    for (int i = blockIdx.x * blockDim.x + threadIdx.x; i < n8; i += stride) {
        f32x4 a = ((const f32x4*)src)[2 * (size_t)i];
        f32x4 b = ((const f32x4*)src)[2 * (size_t)i + 1];
        u16x8 r;
        r[0] = f2bf(a[0]); r[1] = f2bf(a[1]); r[2] = f2bf(a[2]); r[3] = f2bf(a[3]);
        r[4] = f2bf(b[0]); r[5] = f2bf(b[1]); r[6] = f2bf(b[2]); r[7] = f2bf(b[3]);
        ((u16x8*)dst)[i] = r;
    }
}

// ---------------- 8-phase 256^2 GEMM + fused reductions ----------------
// grid = 512 blocks x 512 threads (8 waves, 2M x 4N). Per wave: 128x64 output
// as acc[8][4] 16x16 fragments. LDS 128 KiB: [2 buf][A0,A1,B0,B1 x 16 KiB].
// XCD swizzle: XCD k (= bid%8) owns W col panel k*256 (1 MB, L2-resident).
// Per K-tile t, 4 phases x {ds_read subtile; stage half-tile; s_barrier;
// lgkmcnt(0); setprio(1); 16 MFMA; setprio(0); s_barrier}; vmcnt(6) only at
// the tile boundary (3 half-tiles = 6 loads in flight). Stage plan: P0 stages
// (t+1).A1; P2 stages (t+2).B0 (B region of buf t freed at P1); P3 stages
// (t+2).B1 + (t+2).A0 (A region freed at P2). Region-free safety: the last
// ds_reads of a region are drained by that wave's lgkmcnt(0) before it passes
// the phase-end barrier, which the staging wave must also pass before issuing.
__global__ __launch_bounds__(512, 2)
void gemm8(const u16* __restrict__ xbf, const u16* __restrict__ wbf,
           const float* __restrict__ xdot,
           float* __restrict__ ns_acc, float* __restrict__ sx_acc,
           float* __restrict__ xx_acc) {
    __shared__ u16 lds[65536];   // 128 KiB

    const int tid  = threadIdx.x;
    const int lane = tid & 63;
    const int wid  = tid >> 6;
    const int wr = wid >> 2, wc = wid & 3;     // 2 x 4 wave grid
    const int fr = lane & 15, fq = lane >> 4;

    const int bid  = blockIdx.x;               // 512
    const int brow = (bid >> 3) * 256;
    const int bcol = (bid & 7) * 256;

    // per-thread staging offsets: thread covers row i>>3, 16B slot i&7, for
    // i = tid and 512+tid. Swizzle: global slot ^= (row&7); LDS dest linear.
    const int i0 = tid, i1 = 512 + tid;
    const int r0 = i0 >> 3, sl0 = i0 & 7;
    const int r1 = i1 >> 3, sl1 = i1 & 7;
    const size_t poff0 = (size_t)r0 * DTOT + ((sl0 ^ (r0 & 7)) << 3);
    const size_t poff1 = (size_t)r1 * DTOT + ((sl1 ^ (r1 & 7)) << 3);

    auto stage2 = [&](const u16* base, int ldsbyte) {
        gload_lds16(base + poff0, (char*)lds + ldsbyte + i0 * 16);
        gload_lds16(base + poff1, (char*)lds + ldsbyte + i1 * 16);
    };
    auto stA = [&](int v, int half, int ldsbyte) {      // A half-tile, K-step v
        v = v > NTILES - 1 ? NTILES - 1 : v;            // tail: restage same bytes
        stage2(xbf + (size_t)(brow + half * 128) * DTOT + v * 64, ldsbyte);
    };
    auto stB = [&](int v, int half, int ldsbyte) {
        v = v > NTILES - 1 ? NTILES - 1 : v;
        stage2(wbf + (size_t)(bcol + half * 128) * DTOT + v * 64, ldsbyte);
    };

    // swizzled fragment read (u16-unit index): logical slot s -> physical s^(row&7)
#define FRAG(base_u16, row, s) \
    (*(const bf16x8*)&lds[(base_u16) + (row) * 64 + (((s) ^ ((row) & 7)) << 3)])

    f32x4 acc[8][4] = {};
    bf16x8 Af[2][4], Bf[2][4];

    // ---- prologue: tile 0 fully + tile 1 {B0,B1,A0}
    stA(0, 0, 0);             stA(0, 1, 16384);
    stB(0, 0, 32768);         stB(0, 1, 49152);
    stB(1, 0, 65536 + 32768); stB(1, 1, 65536 + 49152);
    stA(1, 0, 65536 + 0);
    WAITV(6);   // tile 0's 8 loads landed; tile 1's 6 may fly
    BARS();

    for (int t = 0; t < NTILES; ++t) {
        const int cur   = t & 1;
        const int abase = cur * 32768 + wr * 8192;                 // u16 units
        const int bbase = cur * 32768 + 16384 + (wc >> 1) * 8192;
        const int brB   = (wc & 1) * 64;
        const int bufn  = (cur ^ 1) * 65536;   // buf of tile t+1 (bytes)
        const int bufc  = cur * 65536;         // buf of tile t+2 (freed regions)

        // ---- P0: read A[m0-3]+B[n0-1]; stage (t+1).A1
#pragma unroll
        for (int ks = 0; ks < 2; ++ks) {
#pragma unroll
            for (int m = 0; m < 4; ++m) Af[ks][m] = FRAG(abase, m * 16 + fr, ks * 4 + fq);
#pragma unroll
            for (int n = 0; n < 2; ++n) Bf[ks][n] = FRAG(bbase, brB + n * 16 + fr, ks * 4 + fq);
        }
        stA(t + 1, 1, bufn + 16384);
        BARS(); LGKM0();
        __builtin_amdgcn_s_setprio(1);
#pragma unroll
        for (int m = 0; m < 4; ++m)
#pragma unroll
            for (int n = 0; n < 2; ++n)
#pragma unroll
                for (int ks = 0; ks < 2; ++ks)
                    acc[m][n] = __builtin_amdgcn_mfma_f32_16x16x32_bf16(Af[ks][m], Bf[ks][n], acc[m][n], 0, 0, 0);
        __builtin_amdgcn_s_setprio(0);
        BARS();

        // ---- P1: read B[n2-3]; MFMA m0-3 x n2-3 (B region dead after this phase)
#pragma unroll
        for (int ks = 0; ks < 2; ++ks)
#pragma unroll
            for (int n = 0; n < 2; ++n) Bf[ks][2 + n] = FRAG(bbase, brB + (2 + n) * 16 + fr, ks * 4 + fq);
        BARS(); LGKM0();
        __builtin_amdgcn_s_setprio(1);
#pragma unroll
        for (int m = 0; m < 4; ++m)
#pragma unroll
            for (int n = 0; n < 2; ++n)
#pragma unroll
                for (int ks = 0; ks < 2; ++ks)
                    acc[m][2 + n] = __builtin_amdgcn_mfma_f32_16x16x32_bf16(Af[ks][m], Bf[ks][2 + n], acc[m][2 + n], 0, 0, 0);
        __builtin_amdgcn_s_setprio(0);
        BARS();

        // ---- P2: read A[m4-7]; stage (t+2).B0 into freed B region
#pragma unroll
        for (int ks = 0; ks < 2; ++ks)
#pragma unroll
            for (int m = 0; m < 4; ++m) Af[ks][m] = FRAG(abase, 64 + m * 16 + fr, ks * 4 + fq);
        stB(t + 2, 0, bufc + 32768);
        BARS(); LGKM0();
        __builtin_amdgcn_s_setprio(1);
#pragma unroll
        for (int m = 0; m < 4; ++m)
#pragma unroll
            for (int n = 0; n < 2; ++n)
#pragma unroll
                for (int ks = 0; ks < 2; ++ks)
                    acc[4 + m][2 + n] = __builtin_amdgcn_mfma_f32_16x16x32_bf16(Af[ks][m], Bf[ks][2 + n], acc[4 + m][2 + n], 0, 0, 0);
        __builtin_amdgcn_s_setprio(0);
        BARS();

        // ---- P3: stage (t+2).B1 + (t+2).A0 (A freed at P2 barrier); MFMA m4-7 x n0-1
        stB(t + 2, 1, bufc + 49152);
        stA(t + 2, 0, bufc + 0);
        BARS(); LGKM0();
        __builtin_amdgcn_s_setprio(1);
#pragma unroll
        for (int m = 0; m < 4; ++m)
#pragma unroll
            for (int n = 0; n < 2; ++n)
#pragma unroll
                for (int ks = 0; ks < 2; ++ks)
                    acc[4 + m][n] = __builtin_amdgcn_mfma_f32_16x16x32_bf16(Af[ks][m], Bf[ks][n], acc[4 + m][n], 0, 0, 0);
        __builtin_amdgcn_s_setprio(0);
        // boundary: 8 issued this iter; wait so only (t+2)'s 6 remain in flight
        WAITV(6);
        BARS();
    }

    WAITV(0);   // drain clamped tail stages before epilogue
    BARS();

    // Epilogue: C/D layout col = lane&15, row = (lane>>4)*4 + reg (m89-verified).
    // Per (m,j): one output row; reduce s^2, s*xd, xd^2 over fr (shfl_xor),
    // one atomicAdd per row/quantity per wave. Each (b,e) occurs once grid-wide.
#pragma unroll
    for (int m = 0; m < 8; ++m) {
#pragma unroll
        for (int jj = 0; jj < 4; ++jj) {
            const int row = brow + wr * 128 + m * 16 + fq * 4 + jj;
            const float* xp = xdot + (size_t)row * DTOT + bcol + wc * 64 + fr;
            float pns = 0.f, psx = 0.f, pxx = 0.f;
#pragma unroll
            for (int n = 0; n < 4; ++n) {
                float s  = acc[m][n][jj];
                float xv = xp[n * 16];
                pns += s * s; psx += s * xv; pxx += xv * xv;
            }
#pragma unroll
            for (int msk = 1; msk < 16; msk <<= 1) {
                pns += __shfl_xor(pns, msk);
                psx += __shfl_xor(psx, msk);
                pxx += __shfl_xor(pxx, msk);
            }
            if (fr == 0) {
                atomicAdd(&ns_acc[row], pns);
                atomicAdd(&sx_acc[row], psx);
                atomicAdd(&xx_acc[row], pxx);
            }
        }
    }
#undef FRAG
}

__global__ void finalize_k(const float* __restrict__ ns, const float* __restrict__ sx,
                           const float* __restrict__ xx, float* __restrict__ out) {
    int i = blockIdx.x * blockDim.x + threadIdx.x;
    if (i < MTOT) out[i] = xx[i] - (sx[i] * sx[i]) / (1.0f + ns[i]);
}

extern "C" void kernel_launch(void* const* d_in, const int* in_sizes, int n_in,
                              void* d_out, int out_size, void* d_ws, size_t ws_size,
                              hipStream_t stream) {
    const float* x  = (const float*)d_in[0];
    const float* xd = (const float*)d_in[1];
    const float* W  = (const float*)d_in[2];
    float* out = (float*)d_out;

    const size_t xbf_bytes = (size_t)MTOT * DTOT * 2;   // 67.1 MB
    const size_t wbf_bytes = (size_t)DTOT * DTOT * 2;   //  8.4 MB
    const size_t acc_bytes = (size_t)3 * MTOT * 4;      //  0.2 MB

    u16* xbf = (u16*)d_ws;
    u16* wbf = (u16*)((char*)d_ws + xbf_bytes);
    float* accs = (float*)((char*)d_ws + xbf_bytes + wbf_bytes);
    float* nsA = accs;
    float* sxA = accs + MTOT;
    float* xxA = accs + 2 * MTOT;
    (void)ws_size; (void)in_sizes; (void)n_in; (void)out_size;

    hipMemsetAsync(accs, 0, acc_bytes, stream);  // re-zero every call

    cast_kernel<<<2048, 256, 0, stream>>>(x, xbf, MTOT * DTOT / 8);
    cast_kernel<<<512, 256, 0, stream>>>(W, wbf, DTOT * DTOT / 8);
    gemm8<<<512, 512, 0, stream>>>(xbf, wbf, xd, nsA, sxA, xxA);
    finalize_k<<<MTOT / 256, 256, 0, stream>>>(nsA, sxA, xxA, out);
}

// Round 5
// 205.621 us; speedup vs baseline: 1.1554x; 1.0013x over previous
//
#include <hip/hip_runtime.h>
#include <hip/hip_bf16.h>

// out[b] = ||xd_b||^2 - (s_b . xd_b)^2 / (1 + ||s_b||^2), s = x @ W^T.
// bf16 MFMA GEMM, 256x256 tile, BK=64, 8-phase schedule, fused reduction
// epilogue; s never materialized.
// R5: ks-split balanced phases — every phase reads 4 or 8 b128 and issues 16
// INDEPENDENT MFMAs (one ks x one m-quadrant x all n); dependent acc updates
// are 2 phases apart. Stage plan re-derived for new region lifetimes:
// P0 st (t+1).A0, P1 st (t+1).A1 (bufn, write-only), P3 st (t+2).B0+B1
// (bufc B region freed after P2). Boundary vmcnt(4). Casts merged to 1 launch.

#define MTOT 16384
#define DTOT 2048
#define NTILES 32   // DTOT / 64

typedef unsigned short u16;
typedef __attribute__((ext_vector_type(4))) float f32x4;
typedef __attribute__((ext_vector_type(8))) short bf16x8;
typedef __attribute__((ext_vector_type(8))) unsigned short u16x8;

__device__ __forceinline__ u16 f2bf(float f) {
    union { float f; unsigned int u; } v; v.f = f;
    unsigned int u = v.u;
    u += 0x7fffu + ((u >> 16) & 1u);   // RNE (inputs finite)
    return (u16)(u >> 16);
}

__device__ __forceinline__ void gload_lds16(const void* gptr, void* ldsptr) {
    __builtin_amdgcn_global_load_lds(
        (const __attribute__((address_space(1))) unsigned int*)gptr,
        (__attribute__((address_space(3))) unsigned int*)ldsptr,
        16, 0, 0);
}

#define BARS()   __builtin_amdgcn_s_barrier()
#define LGKM0()  asm volatile("s_waitcnt lgkmcnt(0)")
#define WAITV(n) asm volatile("s_waitcnt vmcnt(" #n ")")

// ---------------- cast f32 -> bf16 (x and W in one launch) ----------------
__global__ void cast2_kernel(const float* __restrict__ x, const float* __restrict__ W,
                             u16* __restrict__ xbf, u16* __restrict__ wbf,
                             int nx8, int ntot8) {
    int stride = gridDim.x * blockDim.x;
    for (int i = blockIdx.x * blockDim.x + threadIdx.x; i < ntot8; i += stride) {
        const float* s; u16* d; int j;
        if (i < nx8) { s = x; d = xbf; j = i; }
        else         { s = W; d = wbf; j = i - nx8; }
        f32x4 a = ((const f32x4*)s)[2 * (size_t)j];
        f32x4 b = ((const f32x4*)s)[2 * (size_t)j + 1];
        u16x8 r;
        r[0] = f2bf(a[0]); r[1] = f2bf(a[1]); r[2] = f2bf(a[2]); r[3] = f2bf(a[3]);
        r[4] = f2bf(b[0]); r[5] = f2bf(b[1]); r[6] = f2bf(b[2]); r[7] = f2bf(b[3]);
        ((u16x8*)d)[j] = r;
    }
}

// ---------------- 8-phase 256^2 GEMM + fused reductions ----------------
// grid = 512 blocks x 512 threads (8 waves, 2M x 4N). Per wave: 128x64 output
// as acc[8][4]. LDS 128 KiB: [2 buf][A0,A1,B0,B1 x 16 KiB]. XCD k (= bid%8)
// owns W col panel k*256 (1 MB, L2-resident).
// Phases (per K-tile t): P0 ks0 m0-3 x n0-3; P1 ks0 m4-7; P2 ks1 m0-3;
// P3 ks1 m4-7. Reads/phase: 8/4/8/4 b128; 16 independent MFMA each.
// Region lifetimes: bufc.B last ds_read at P2; bufc.A last at P3.
// Stages: P0 (t+1).A0 -> bufn (write-only buf; its A was last read at t-1 P3,
// drained by that lgkmcnt(0) + boundary barrier); P1 (t+1).A1 -> bufn;
// P3 (t+2).B0+B1 -> bufc.B (freed at P2 lgkmcnt(0) + P2-end barrier).
// Boundary: issued/tile = 8; in-flight pre-wait = 4 (prev (t+1).B) + 8;
// vmcnt(4) drains prev.B + A0 + A1 -> buf(t+1) complete; (t+2).B still flying.
__global__ __launch_bounds__(512, 2)
void gemm8(const u16* __restrict__ xbf, const u16* __restrict__ wbf,
           const float* __restrict__ xdot,
           float* __restrict__ ns_acc, float* __restrict__ sx_acc,
           float* __restrict__ xx_acc) {
    __shared__ u16 lds[65536];   // 128 KiB

    const int tid  = threadIdx.x;
    const int lane = tid & 63;
    const int wid  = tid >> 6;
    const int wr = wid >> 2, wc = wid & 3;     // 2 x 4 wave grid
    const int fr = lane & 15, fq = lane >> 4;

    const int bid  = blockIdx.x;               // 512
    const int brow = (bid >> 3) * 256;
    const int bcol = (bid & 7) * 256;

    // staging: thread covers row i>>3, 16B slot i&7, i = tid and 512+tid.
    // Swizzle: global slot ^= (row&7); LDS dest linear (gload_lds constraint).
    const int i0 = tid, i1 = 512 + tid;
    const int r0 = i0 >> 3, sl0 = i0 & 7;
    const int r1 = i1 >> 3, sl1 = i1 & 7;
    const size_t poff0 = (size_t)r0 * DTOT + ((sl0 ^ (r0 & 7)) << 3);
    const size_t poff1 = (size_t)r1 * DTOT + ((sl1 ^ (r1 & 7)) << 3);

    auto stage2 = [&](const u16* base, int ldsbyte) {
        gload_lds16(base + poff0, (char*)lds + ldsbyte + i0 * 16);
        gload_lds16(base + poff1, (char*)lds + ldsbyte + i1 * 16);
    };
    auto stA = [&](int v, int half, int ldsbyte) {      // A half-tile, K-step v
        v = v > NTILES - 1 ? NTILES - 1 : v;            // tail: idempotent restage
        stage2(xbf + (size_t)(brow + half * 128) * DTOT + v * 64, ldsbyte);
    };
    auto stB = [&](int v, int half, int ldsbyte) {
        v = v > NTILES - 1 ? NTILES - 1 : v;
        stage2(wbf + (size_t)(bcol + half * 128) * DTOT + v * 64, ldsbyte);
    };

    // swizzled fragment read: logical slot s -> physical s^(row&7). Note
    // row = m*16+fr => row&7 = fr&7 (lane-invariant across m): compiler folds
    // the XOR into the per-lane base; reads become base + imm offsets.
#define FRAG(base_u16, row, s) \
    (*(const bf16x8*)&lds[(base_u16) + (row) * 64 + (((s) ^ ((row) & 7)) << 3)])

    f32x4 acc[8][4] = {};
    bf16x8 Af[4], Ag[4], Bf[4];

    // ---- prologue: tile 0 fully + tile 1 {B0,B1}
    stA(0, 0, 0);             stA(0, 1, 16384);
    stB(0, 0, 32768);         stB(0, 1, 49152);
    stB(1, 0, 65536 + 32768); stB(1, 1, 65536 + 49152);
    WAITV(4);   // tile 0's 8 landed; tile 1's B (4) may fly
    BARS();

    for (int t = 0; t < NTILES; ++t) {
        const int cur   = t & 1;
        const int abase = cur * 32768 + wr * 8192;                 // u16 units
        const int bbase = cur * 32768 + 16384 + (wc >> 1) * 8192;
        const int brB   = (wc & 1) * 64;
        const int bufn  = (cur ^ 1) * 65536;   // buf of tile t+1 (bytes)
        const int bufc  = cur * 65536;         // current buf (B freed at P2)

        // ---- P0: read ks0 A[m0-3] + B[n0-3] (8); stage (t+1).A0; MFMA 16
#pragma unroll
        for (int m = 0; m < 4; ++m) Af[m] = FRAG(abase, m * 16 + fr, fq);
#pragma unroll
        for (int n = 0; n < 4; ++n) Bf[n] = FRAG(bbase, brB + n * 16 + fr, fq);
        stA(t + 1, 0, bufn + 0);
        BARS(); LGKM0();
        __builtin_amdgcn_s_setprio(1);
#pragma unroll
        for (int m = 0; m < 4; ++m)
#pragma unroll
            for (int n = 0; n < 4; ++n)
                acc[m][n] = __builtin_amdgcn_mfma_f32_16x16x32_bf16(Af[m], Bf[n], acc[m][n], 0, 0, 0);
        __builtin_amdgcn_s_setprio(0);
        BARS();

        // ---- P1: read ks0 A[m4-7] (4); stage (t+1).A1; MFMA 16
#pragma unroll
        for (int m = 0; m < 4; ++m) Ag[m] = FRAG(abase, 64 + m * 16 + fr, fq);
        stA(t + 1, 1, bufn + 16384);
        BARS(); LGKM0();
        __builtin_amdgcn_s_setprio(1);
#pragma unroll
        for (int m = 0; m < 4; ++m)
#pragma unroll
            for (int n = 0; n < 4; ++n)
                acc[4 + m][n] = __builtin_amdgcn_mfma_f32_16x16x32_bf16(Ag[m], Bf[n], acc[4 + m][n], 0, 0, 0);
        __builtin_amdgcn_s_setprio(0);
        BARS();

        // ---- P2: read ks1 A[m0-3] + B[n0-3] (8); no stage; MFMA 16
        //      (last B-region ds_reads -> B freed after this phase's barrier)
#pragma unroll
        for (int m = 0; m < 4; ++m) Af[m] = FRAG(abase, m * 16 + fr, 4 + fq);
#pragma unroll
        for (int n = 0; n < 4; ++n) Bf[n] = FRAG(bbase, brB + n * 16 + fr, 4 + fq);
        BARS(); LGKM0();
        __builtin_amdgcn_s_setprio(1);
#pragma unroll
        for (int m = 0; m < 4; ++m)
#pragma unroll
            for (int n = 0; n < 4; ++n)
                acc[m][n] = __builtin_amdgcn_mfma_f32_16x16x32_bf16(Af[m], Bf[n], acc[m][n], 0, 0, 0);
        __builtin_amdgcn_s_setprio(0);
        BARS();

        // ---- P3: read ks1 A[m4-7] (4); stage (t+2).B0+B1 into freed B; MFMA 16
#pragma unroll
        for (int m = 0; m < 4; ++m) Ag[m] = FRAG(abase, 64 + m * 16 + fr, 4 + fq);
        stB(t + 2, 0, bufc + 32768);
        stB(t + 2, 1, bufc + 49152);
        BARS(); LGKM0();
        __builtin_amdgcn_s_setprio(1);
#pragma unroll
        for (int m = 0; m < 4; ++m)
#pragma unroll
            for (int n = 0; n < 4; ++n)
                acc[4 + m][n] = __builtin_amdgcn_mfma_f32_16x16x32_bf16(Ag[m], Bf[n], acc[4 + m][n], 0, 0, 0);
        __builtin_amdgcn_s_setprio(0);
        // boundary: drain prev.B + (t+1).A0 + (t+1).A1; leave (t+2).B flying
        WAITV(4);
        BARS();
    }

    WAITV(0);   // drain clamped tail stages before epilogue
    BARS();

    // Epilogue: C/D layout col = lane&15, row = (lane>>4)*4 + reg (m89-verified).
    // Reduce s^2, s*xd, xd^2 over fr (shfl_xor); 1 atomicAdd/row/qty/wave.
#pragma unroll
    for (int m = 0; m < 8; ++m) {
#pragma unroll
        for (int jj = 0; jj < 4; ++jj) {
            const int row = brow + wr * 128 + m * 16 + fq * 4 + jj;
            const float* xp = xdot + (size_t)row * DTOT + bcol + wc * 64 + fr;
            float pns = 0.f, psx = 0.f, pxx = 0.f;
#pragma unroll
            for (int n = 0; n < 4; ++n) {
                float s  = acc[m][n][jj];
                float xv = xp[n * 16];
                pns += s * s; psx += s * xv; pxx += xv * xv;
            }
#pragma unroll
            for (int msk = 1; msk < 16; msk <<= 1) {
                pns += __shfl_xor(pns, msk);
                psx += __shfl_xor(psx, msk);
                pxx += __shfl_xor(pxx, msk);
            }
            if (fr == 0) {
                atomicAdd(&ns_acc[row], pns);
                atomicAdd(&sx_acc[row], psx);
                atomicAdd(&xx_acc[row], pxx);
            }
        }
    }
#undef FRAG
}

__global__ void finalize_k(const float* __restrict__ ns, const float* __restrict__ sx,
                           const float* __restrict__ xx, float* __restrict__ out) {
    int i = blockIdx.x * blockDim.x + threadIdx.x;
    if (i < MTOT) out[i] = xx[i] - (sx[i] * sx[i]) / (1.0f + ns[i]);
}

extern "C" void kernel_launch(void* const* d_in, const int* in_sizes, int n_in,
                              void* d_out, int out_size, void* d_ws, size_t ws_size,
                              hipStream_t stream) {
    const float* x  = (const float*)d_in[0];
    const float* xd = (const float*)d_in[1];
    const float* W  = (const float*)d_in[2];
    float* out = (float*)d_out;

    const size_t xbf_bytes = (size_t)MTOT * DTOT * 2;   // 67.1 MB
    const size_t wbf_bytes = (size_t)DTOT * DTOT * 2;   //  8.4 MB
    const size_t acc_bytes = (size_t)3 * MTOT * 4;      //  0.2 MB

    u16* xbf = (u16*)d_ws;
    u16* wbf = (u16*)((char*)d_ws + xbf_bytes);
    float* accs = (float*)((char*)d_ws + xbf_bytes + wbf_bytes);
    float* nsA = accs;
    float* sxA = accs + MTOT;
    float* xxA = accs + 2 * MTOT;
    (void)ws_size; (void)in_sizes; (void)n_in; (void)out_size;

    hipMemsetAsync(accs, 0, acc_bytes, stream);  // re-zero every call

    const int nx8 = MTOT * DTOT / 8, nw8 = DTOT * DTOT / 8;
    cast2_kernel<<<2048, 256, 0, stream>>>(x, W, xbf, wbf, nx8, nx8 + nw8);
    gemm8<<<512, 512, 0, stream>>>(xbf, wbf, xd, nsA, sxA, xxA);
    finalize_k<<<MTOT / 256, 256, 0, stream>>>(nsA, sxA, xxA, out);
}

// Round 6
// 205.277 us; speedup vs baseline: 1.1573x; 1.0017x over previous
//
#include <hip/hip_runtime.h>
#include <hip/hip_bf16.h>

// out[b] = ||xd_b||^2 - (s_b . xd_b)^2 / (1 + ||s_b||^2), s = x @ W^T.
// bf16 MFMA GEMM, 256x256 tile, BK=64, 8-phase schedule, fused reduction
// epilogue; s never materialized.
// R6 = R5 + sched_barrier(0) pin before every s_barrier in the K-loop.
// Rationale: __builtin_amdgcn_s_barrier is NOT a compiler scheduling fence;
// LLVM can sink the phase's ds_read issues below the barrier into the MFMA
// region, serializing LDS pipe and matrix pipe per wave (observed ~34%
// MfmaUtil across R2/R4/R5). sched_barrier(0) pins issue order at compile
// time with zero runtime cost.

#define MTOT 16384
#define DTOT 2048
#define NTILES 32   // DTOT / 64

typedef unsigned short u16;
typedef __attribute__((ext_vector_type(4))) float f32x4;
typedef __attribute__((ext_vector_type(8))) short bf16x8;
typedef __attribute__((ext_vector_type(8))) unsigned short u16x8;

__device__ __forceinline__ u16 f2bf(float f) {
    union { float f; unsigned int u; } v; v.f = f;
    unsigned int u = v.u;
    u += 0x7fffu + ((u >> 16) & 1u);   // RNE (inputs finite)
    return (u16)(u >> 16);
}

__device__ __forceinline__ void gload_lds16(const void* gptr, void* ldsptr) {
    __builtin_amdgcn_global_load_lds(
        (const __attribute__((address_space(1))) unsigned int*)gptr,
        (__attribute__((address_space(3))) unsigned int*)ldsptr,
        16, 0, 0);
}

#define BARS()   __builtin_amdgcn_s_barrier()
#define SCHED0() __builtin_amdgcn_sched_barrier(0)
#define LGKM0()  asm volatile("s_waitcnt lgkmcnt(0)")
#define WAITV(n) asm volatile("s_waitcnt vmcnt(" #n ")")

// ---------------- cast f32 -> bf16 (x and W in one launch) ----------------
__global__ void cast2_kernel(const float* __restrict__ x, const float* __restrict__ W,
                             u16* __restrict__ xbf, u16* __restrict__ wbf,
                             int nx8, int ntot8) {
    int stride = gridDim.x * blockDim.x;
    for (int i = blockIdx.x * blockDim.x + threadIdx.x; i < ntot8; i += stride) {
        const float* s; u16* d; int j;
        if (i < nx8) { s = x; d = xbf; j = i; }
        else         { s = W; d = wbf; j = i - nx8; }
        f32x4 a = ((const f32x4*)s)[2 * (size_t)j];
        f32x4 b = ((const f32x4*)s)[2 * (size_t)j + 1];
        u16x8 r;
        r[0] = f2bf(a[0]); r[1] = f2bf(a[1]); r[2] = f2bf(a[2]); r[3] = f2bf(a[3]);
        r[4] = f2bf(b[0]); r[5] = f2bf(b[1]); r[6] = f2bf(b[2]); r[7] = f2bf(b[3]);
        ((u16x8*)d)[j] = r;
    }
}

// ---------------- 8-phase 256^2 GEMM + fused reductions ----------------
// grid = 512 blocks x 512 threads (8 waves, 2M x 4N). Per wave: 128x64 output
// as acc[8][4]. LDS 128 KiB: [2 buf][A0,A1,B0,B1 x 16 KiB]. XCD k (= bid%8)
// owns W col panel k*256 (1 MB, L2-resident).
// Phases (per K-tile t): P0 ks0 m0-3; P1 ks0 m4-7; P2 ks1 m0-3; P3 ks1 m4-7.
// Reads/phase: 8/4/8/4 b128; 16 independent MFMA each. Stages: P0 (t+1).A0,
// P1 (t+1).A1 (bufn write-only), P3 (t+2).B0+B1 (bufc.B freed after P2).
// Boundary vmcnt(4): drains prev.B + (t+1).A0/A1, leaves (t+2).B flying.
__global__ __launch_bounds__(512, 2)
void gemm8(const u16* __restrict__ xbf, const u16* __restrict__ wbf,
           const float* __restrict__ xdot,
           float* __restrict__ ns_acc, float* __restrict__ sx_acc,
           float* __restrict__ xx_acc) {
    __shared__ u16 lds[65536];   // 128 KiB

    const int tid  = threadIdx.x;
    const int lane = tid & 63;
    const int wid  = tid >> 6;
    const int wr = wid >> 2, wc = wid & 3;     // 2 x 4 wave grid
    const int fr = lane & 15, fq = lane >> 4;

    const int bid  = blockIdx.x;               // 512
    const int brow = (bid >> 3) * 256;
    const int bcol = (bid & 7) * 256;

    // staging: thread covers row i>>3, 16B slot i&7, i = tid and 512+tid.
    // Swizzle: global slot ^= (row&7); LDS dest linear (gload_lds constraint).
    const int i0 = tid, i1 = 512 + tid;
    const int r0 = i0 >> 3, sl0 = i0 & 7;
    const int r1 = i1 >> 3, sl1 = i1 & 7;
    const size_t poff0 = (size_t)r0 * DTOT + ((sl0 ^ (r0 & 7)) << 3);
    const size_t poff1 = (size_t)r1 * DTOT + ((sl1 ^ (r1 & 7)) << 3);

    auto stage2 = [&](const u16* base, int ldsbyte) {
        gload_lds16(base + poff0, (char*)lds + ldsbyte + i0 * 16);
        gload_lds16(base + poff1, (char*)lds + ldsbyte + i1 * 16);
    };
    auto stA = [&](int v, int half, int ldsbyte) {      // A half-tile, K-step v
        v = v > NTILES - 1 ? NTILES - 1 : v;            // tail: idempotent restage
        stage2(xbf + (size_t)(brow + half * 128) * DTOT + v * 64, ldsbyte);
    };
    auto stB = [&](int v, int half, int ldsbyte) {
        v = v > NTILES - 1 ? NTILES - 1 : v;
        stage2(wbf + (size_t)(bcol + half * 128) * DTOT + v * 64, ldsbyte);
    };

    // swizzled fragment read: logical slot s -> physical s^(row&7); row&7 is
    // lane-invariant across m/n (= fr&7), so the XOR folds into the base.
#define FRAG(base_u16, row, s) \
    (*(const bf16x8*)&lds[(base_u16) + (row) * 64 + (((s) ^ ((row) & 7)) << 3)])

    f32x4 acc[8][4] = {};
    bf16x8 Af[4], Ag[4], Bf[4];

    // ---- prologue: tile 0 fully + tile 1 {B0,B1}
    stA(0, 0, 0);             stA(0, 1, 16384);
    stB(0, 0, 32768);         stB(0, 1, 49152);
    stB(1, 0, 65536 + 32768); stB(1, 1, 65536 + 49152);
    WAITV(4);   // tile 0's 8 landed; tile 1's B (4) may fly
    SCHED0();
    BARS();

    for (int t = 0; t < NTILES; ++t) {
        const int cur   = t & 1;
        const int abase = cur * 32768 + wr * 8192;                 // u16 units
        const int bbase = cur * 32768 + 16384 + (wc >> 1) * 8192;
        const int brB   = (wc & 1) * 64;
        const int bufn  = (cur ^ 1) * 65536;   // buf of tile t+1 (bytes)
        const int bufc  = cur * 65536;         // current buf (B freed at P2)

        // ---- P0: read ks0 A[m0-3] + B[n0-3] (8); stage (t+1).A0; MFMA 16
#pragma unroll
        for (int m = 0; m < 4; ++m) Af[m] = FRAG(abase, m * 16 + fr, fq);
#pragma unroll
        for (int n = 0; n < 4; ++n) Bf[n] = FRAG(bbase, brB + n * 16 + fr, fq);
        stA(t + 1, 0, bufn + 0);
        SCHED0(); BARS(); LGKM0();
        __builtin_amdgcn_s_setprio(1);
#pragma unroll
        for (int m = 0; m < 4; ++m)
#pragma unroll
            for (int n = 0; n < 4; ++n)
                acc[m][n] = __builtin_amdgcn_mfma_f32_16x16x32_bf16(Af[m], Bf[n], acc[m][n], 0, 0, 0);
        __builtin_amdgcn_s_setprio(0);
        SCHED0(); BARS();

        // ---- P1: read ks0 A[m4-7] (4); stage (t+1).A1; MFMA 16
#pragma unroll
        for (int m = 0; m < 4; ++m) Ag[m] = FRAG(abase, 64 + m * 16 + fr, fq);
        stA(t + 1, 1, bufn + 16384);
        SCHED0(); BARS(); LGKM0();
        __builtin_amdgcn_s_setprio(1);
#pragma unroll
        for (int m = 0; m < 4; ++m)
#pragma unroll
            for (int n = 0; n < 4; ++n)
                acc[4 + m][n] = __builtin_amdgcn_mfma_f32_16x16x32_bf16(Ag[m], Bf[n], acc[4 + m][n], 0, 0, 0);
        __builtin_amdgcn_s_setprio(0);
        SCHED0(); BARS();

        // ---- P2: read ks1 A[m0-3] + B[n0-3] (8); no stage; MFMA 16
        //      (last B-region ds_reads -> B freed after this phase's barrier)
#pragma unroll
        for (int m = 0; m < 4; ++m) Af[m] = FRAG(abase, m * 16 + fr, 4 + fq);
#pragma unroll
        for (int n = 0; n < 4; ++n) Bf[n] = FRAG(bbase, brB + n * 16 + fr, 4 + fq);
        SCHED0(); BARS(); LGKM0();
        __builtin_amdgcn_s_setprio(1);
#pragma unroll
        for (int m = 0; m < 4; ++m)
#pragma unroll
            for (int n = 0; n < 4; ++n)
                acc[m][n] = __builtin_amdgcn_mfma_f32_16x16x32_bf16(Af[m], Bf[n], acc[m][n], 0, 0, 0);
        __builtin_amdgcn_s_setprio(0);
        SCHED0(); BARS();

        // ---- P3: read ks1 A[m4-7] (4); stage (t+2).B0+B1 into freed B; MFMA 16
#pragma unroll
        for (int m = 0; m < 4; ++m) Ag[m] = FRAG(abase, 64 + m * 16 + fr, 4 + fq);
        stB(t + 2, 0, bufc + 32768);
        stB(t + 2, 1, bufc + 49152);
        SCHED0(); BARS(); LGKM0();
        __builtin_amdgcn_s_setprio(1);
#pragma unroll
        for (int m = 0; m < 4; ++m)
#pragma unroll
            for (int n = 0; n < 4; ++n)
                acc[4 + m][n] = __builtin_amdgcn_mfma_f32_16x16x32_bf16(Ag[m], Bf[n], acc[4 + m][n], 0, 0, 0);
        __builtin_amdgcn_s_setprio(0);
        // boundary: drain prev.B + (t+1).A0 + (t+1).A1; leave (t+2).B flying
        WAITV(4);
        SCHED0(); BARS();
    }

    WAITV(0);   // drain clamped tail stages before epilogue
    BARS();

    // Epilogue: C/D layout col = lane&15, row = (lane>>4)*4 + reg (m89-verified).
    // Reduce s^2, s*xd, xd^2 over fr (shfl_xor); 1 atomicAdd/row/qty/wave.
#pragma unroll
    for (int m = 0; m < 8; ++m) {
#pragma unroll
        for (int jj = 0; jj < 4; ++jj) {
            const int row = brow + wr * 128 + m * 16 + fq * 4 + jj;
            const float* xp = xdot + (size_t)row * DTOT + bcol + wc * 64 + fr;
            float pns = 0.f, psx = 0.f, pxx = 0.f;
#pragma unroll
            for (int n = 0; n < 4; ++n) {
                float s  = acc[m][n][jj];
                float xv = xp[n * 16];
                pns += s * s; psx += s * xv; pxx += xv * xv;
            }
#pragma unroll
            for (int msk = 1; msk < 16; msk <<= 1) {
                pns += __shfl_xor(pns, msk);
                psx += __shfl_xor(psx, msk);
                pxx += __shfl_xor(pxx, msk);
            }
            if (fr == 0) {
                atomicAdd(&ns_acc[row], pns);
                atomicAdd(&sx_acc[row], psx);
                atomicAdd(&xx_acc[row], pxx);
            }
        }
    }
#undef FRAG
}

__global__ void finalize_k(const float* __restrict__ ns, const float* __restrict__ sx,
                           const float* __restrict__ xx, float* __restrict__ out) {
    int i = blockIdx.x * blockDim.x + threadIdx.x;
    if (i < MTOT) out[i] = xx[i] - (sx[i] * sx[i]) / (1.0f + ns[i]);
}

extern "C" void kernel_launch(void* const* d_in, const int* in_sizes, int n_in,
                              void* d_out, int out_size, void* d_ws, size_t ws_size,
                              hipStream_t stream) {
    const float* x  = (const float*)d_in[0];
    const float* xd = (const float*)d_in[1];
    const float* W  = (const float*)d_in[2];
    float* out = (float*)d_out;

    const size_t xbf_bytes = (size_t)MTOT * DTOT * 2;   // 67.1 MB
    const size_t wbf_bytes = (size_t)DTOT * DTOT * 2;   //  8.4 MB
    const size_t acc_bytes = (size_t)3 * MTOT * 4;      //  0.2 MB

    u16* xbf = (u16*)d_ws;
    u16* wbf = (u16*)((char*)d_ws + xbf_bytes);
    float* accs = (float*)((char*)d_ws + xbf_bytes + wbf_bytes);
    float* nsA = accs;
    float* sxA = accs + MTOT;
    float* xxA = accs + 2 * MTOT;
    (void)ws_size; (void)in_sizes; (void)n_in; (void)out_size;

    hipMemsetAsync(accs, 0, acc_bytes, stream);  // re-zero every call

    const int nx8 = MTOT * DTOT / 8, nw8 = DTOT * DTOT / 8;
    cast2_kernel<<<2048, 256, 0, stream>>>(x, W, xbf, wbf, nx8, nx8 + nw8);
    gemm8<<<512, 512, 0, stream>>>(xbf, wbf, xd, nsA, sxA, xxA);
    finalize_k<<<MTOT / 256, 256, 0, stream>>>(nsA, sxA, xxA, out);
}

// Round 7
// 202.706 us; speedup vs baseline: 1.1720x; 1.0127x over previous
//
#include <hip/hip_runtime.h>
#include <hip/hip_bf16.h>

// out[b] = ||xd_b||^2 - (s_b . xd_b)^2 / (1 + ||s_b||^2), s = x @ W^T.
// bf16 MFMA GEMM, 256x256 tile, BK=64, fused reduction epilogue.
// R7: one-phase-deep fragment pipelining with COUNTED lgkm waits.
// Every phase p issues phase p+1's ds_reads, then MFMAs on fragments read in
// phase p-1. The compiler's auto-waitcnt emits lgkmcnt(N_newer) -- a counted
// wait -- so the LDS pipe services p+1's reads WHILE the matrix pipe runs p.
// (R2-R6 all had a full lgkmcnt(0) drain per phase after the rendezvous ->
// LDS burst and MFMA strictly alternated; m218's counted-vs-drain0 lever.)
// 4 barriers/tile; boundary = vmcnt(0)+barrier at P2-end, before P3 reads
// the next buffer. Register sets: Af/Ag reused across ks (HW WAR interlock),
// Bf2 separate (loaded at P1 while Bf still feeds P1's MFMA).

#define MTOT 16384
#define DTOT 2048
#define NTILES 32   // DTOT / 64

typedef unsigned short u16;
typedef __attribute__((ext_vector_type(4))) float f32x4;
typedef __attribute__((ext_vector_type(8))) short bf16x8;
typedef __attribute__((ext_vector_type(8))) unsigned short u16x8;

__device__ __forceinline__ u16 f2bf(float f) {
    union { float f; unsigned int u; } v; v.f = f;
    unsigned int u = v.u;
    u += 0x7fffu + ((u >> 16) & 1u);   // RNE (inputs finite)
    return (u16)(u >> 16);
}

__device__ __forceinline__ void gload_lds16(const void* gptr, void* ldsptr) {
    __builtin_amdgcn_global_load_lds(
        (const __attribute__((address_space(1))) unsigned int*)gptr,
        (__attribute__((address_space(3))) unsigned int*)ldsptr,
        16, 0, 0);
}

#define BARS()   __builtin_amdgcn_s_barrier()
#define SCHED0() __builtin_amdgcn_sched_barrier(0)
#define WAITV(n) asm volatile("s_waitcnt vmcnt(" #n ")")

// ---------------- cast f32 -> bf16 (x and W in one launch) ----------------
__global__ void cast2_kernel(const float* __restrict__ x, const float* __restrict__ W,
                             u16* __restrict__ xbf, u16* __restrict__ wbf,
                             int nx8, int ntot8) {
    int stride = gridDim.x * blockDim.x;
    for (int i = blockIdx.x * blockDim.x + threadIdx.x; i < ntot8; i += stride) {
        const float* s; u16* d; int j;
        if (i < nx8) { s = x; d = xbf; j = i; }
        else         { s = W; d = wbf; j = i - nx8; }
        f32x4 a = ((const f32x4*)s)[2 * (size_t)j];
        f32x4 b = ((const f32x4*)s)[2 * (size_t)j + 1];
        u16x8 r;
        r[0] = f2bf(a[0]); r[1] = f2bf(a[1]); r[2] = f2bf(a[2]); r[3] = f2bf(a[3]);
        r[4] = f2bf(b[0]); r[5] = f2bf(b[1]); r[6] = f2bf(b[2]); r[7] = f2bf(b[3]);
        ((u16x8*)d)[j] = r;
    }
}

// ---------------- pipelined 256^2 GEMM + fused reductions ----------------
// grid = 512 blocks x 512 threads (8 waves, 2M x 4N). acc[8][4] per wave.
// LDS 128 KiB: [2 buf][A0,A1,B0,B1 x 16 KiB]. XCD k (= bid%8) owns W col
// panel k*256 (1 MB, L2-resident).
// Phase plan per tile t (1 barrier each; MFMA consumes prev phase's reads):
//  P0: read Ag(ks0,A4-7);  stage (t+1).A0+A1;  MFMA acc[0-3] += Af x Bf (ks0)
//  P1: read Af(ks1,A0-3) + Bf2(ks1,B0-3);      MFMA acc[4-7] += Ag x Bf (ks0)
//  P2: read Ag(ks1,A4-7);                      MFMA acc[0-3] += Af x Bf2 (ks1)
//      vmcnt(0) [all in-flight = buf(t+1) pieces] + barrier  <- boundary
//  P3: read Af,Bf(ks0) from buf(t+1); stage (t+2).B0+B1;
//                                              MFMA acc[4-7] += Ag x Bf2 (ks1)
// Region/WAR safety (1 barrier per phase):
//  - stA(t+1) @P0 into bufn.A: last bufn.A reads (Ag ks1) issued P2@t-1,
//    drained by P3@t-1's auto-lgkm, collective at P3-end barrier. OK.
//  - stB(t+2) @P3 into bufc.B: last bufc.B reads (Bf2) issued P1@t, drained
//    by P2's auto-lgkm, collective at P2-end barrier. OK.
//  - P3's reads of buf(t+1): per-wave vmcnt(0) + boundary barrier make all
//    waves' stages of buf(t+1) collectively complete. OK.
//  - Tail clamp restages identical bytes (idempotent). OK.
__global__ __launch_bounds__(512, 2)
void gemm8(const u16* __restrict__ xbf, const u16* __restrict__ wbf,
           const float* __restrict__ xdot,
           float* __restrict__ ns_acc, float* __restrict__ sx_acc,
           float* __restrict__ xx_acc) {
    __shared__ u16 lds[65536];   // 128 KiB

    const int tid  = threadIdx.x;
    const int lane = tid & 63;
    const int wid  = tid >> 6;
    const int wr = wid >> 2, wc = wid & 3;     // 2 x 4 wave grid
    const int fr = lane & 15, fq = lane >> 4;

    const int bid  = blockIdx.x;               // 512
    const int brow = (bid >> 3) * 256;
    const int bcol = (bid & 7) * 256;

    // staging: thread covers row i>>3, 16B slot i&7, i = tid and 512+tid.
    // Swizzle: global slot ^= (row&7); LDS dest linear (gload_lds constraint).
    const int i0 = tid, i1 = 512 + tid;
    const int r0 = i0 >> 3, sl0 = i0 & 7;
    const int r1 = i1 >> 3, sl1 = i1 & 7;
    const size_t poff0 = (size_t)r0 * DTOT + ((sl0 ^ (r0 & 7)) << 3);
    const size_t poff1 = (size_t)r1 * DTOT + ((sl1 ^ (r1 & 7)) << 3);

    auto stage2 = [&](const u16* base, int ldsbyte) {
        gload_lds16(base + poff0, (char*)lds + ldsbyte + i0 * 16);
        gload_lds16(base + poff1, (char*)lds + ldsbyte + i1 * 16);
    };
    auto stA = [&](int v, int half, int ldsbyte) {      // A half-tile, K-step v
        v = v > NTILES - 1 ? NTILES - 1 : v;            // tail: idempotent restage
        stage2(xbf + (size_t)(brow + half * 128) * DTOT + v * 64, ldsbyte);
    };
    auto stB = [&](int v, int half, int ldsbyte) {
        v = v > NTILES - 1 ? NTILES - 1 : v;
        stage2(wbf + (size_t)(bcol + half * 128) * DTOT + v * 64, ldsbyte);
    };

    // swizzled fragment read: logical slot s -> physical s^(row&7); row&7 is
    // lane-invariant across m/n (= fr&7), so the XOR folds into the base.
#define FRAG(base_u16, row, s) \
    (*(const bf16x8*)&lds[(base_u16) + (row) * 64 + (((s) ^ ((row) & 7)) << 3)])

    f32x4 acc[8][4] = {};
    bf16x8 Af[4], Ag[4], Bf[4], Bf2[4];

    // ---- prologue: stage tile0 {A0,A1,B0,B1} + tile1 {B0,B1}
    stA(0, 0, 0);             stA(0, 1, 16384);
    stB(0, 0, 32768);         stB(0, 1, 49152);
    stB(1, 0, 65536 + 32768); stB(1, 1, 65536 + 49152);
    WAITV(4);   // drain buf0's 8; tile1's B (4) stays in flight
    SCHED0();
    BARS();
    SCHED0();
    // initial fragment reads: ks0 Af/Bf of tile 0
    {
        const int abase = wr * 8192;
        const int bbase = 16384 + (wc >> 1) * 8192;
        const int brB   = (wc & 1) * 64;
#pragma unroll
        for (int m = 0; m < 4; ++m) Af[m] = FRAG(abase, m * 16 + fr, fq);
#pragma unroll
        for (int n = 0; n < 4; ++n) Bf[n] = FRAG(bbase, brB + n * 16 + fr, fq);
    }

    for (int t = 0; t < NTILES; ++t) {
        const int cur    = t & 1;
        const int abase  = cur * 32768 + wr * 8192;                 // u16 units
        const int bbase  = cur * 32768 + 16384 + (wc >> 1) * 8192;
        const int nabase = (cur ^ 1) * 32768 + wr * 8192;           // next buf
        const int nbbase = (cur ^ 1) * 32768 + 16384 + (wc >> 1) * 8192;
        const int brB    = (wc & 1) * 64;
        const int bufn   = (cur ^ 1) * 65536;   // buf of tile t+1 (bytes)
        const int bufc   = cur * 65536;         // current buf (B freed at P2)

        // ---- P0: issue Ag(ks0); stage (t+1).A0+A1; MFMA acc[0-3] += Af*Bf
#pragma unroll
        for (int m = 0; m < 4; ++m) Ag[m] = FRAG(abase, 64 + m * 16 + fr, fq);
        stA(t + 1, 0, bufn + 0);
        stA(t + 1, 1, bufn + 16384);
        SCHED0();
        __builtin_amdgcn_s_setprio(1);
#pragma unroll
        for (int m = 0; m < 4; ++m)
#pragma unroll
            for (int n = 0; n < 4; ++n)
                acc[m][n] = __builtin_amdgcn_mfma_f32_16x16x32_bf16(Af[m], Bf[n], acc[m][n], 0, 0, 0);
        __builtin_amdgcn_s_setprio(0);
        SCHED0(); BARS();

        // ---- P1: issue Af(ks1)+Bf2(ks1); MFMA acc[4-7] += Ag*Bf (ks0)
#pragma unroll
        for (int m = 0; m < 4; ++m) Af[m] = FRAG(abase, m * 16 + fr, 4 + fq);
#pragma unroll
        for (int n = 0; n < 4; ++n) Bf2[n] = FRAG(bbase, brB + n * 16 + fr, 4 + fq);
        SCHED0();
        __builtin_amdgcn_s_setprio(1);
#pragma unroll
        for (int m = 0; m < 4; ++m)
#pragma unroll
            for (int n = 0; n < 4; ++n)
                acc[4 + m][n] = __builtin_amdgcn_mfma_f32_16x16x32_bf16(Ag[m], Bf[n], acc[4 + m][n], 0, 0, 0);
        __builtin_amdgcn_s_setprio(0);
        SCHED0(); BARS();

        // ---- P2: issue Ag(ks1); MFMA acc[0-3] += Af*Bf2 (ks1); boundary
#pragma unroll
        for (int m = 0; m < 4; ++m) Ag[m] = FRAG(abase, 64 + m * 16 + fr, 4 + fq);
        SCHED0();
        __builtin_amdgcn_s_setprio(1);
#pragma unroll
        for (int m = 0; m < 4; ++m)
#pragma unroll
            for (int n = 0; n < 4; ++n)
                acc[m][n] = __builtin_amdgcn_mfma_f32_16x16x32_bf16(Af[m], Bf2[n], acc[m][n], 0, 0, 0);
        __builtin_amdgcn_s_setprio(0);
        SCHED0();
        WAITV(0);   // in-flight = exactly buf(t+1)'s pieces (B@P3(t-1), A@P0(t))
        BARS();     // collective: buf(t+1) complete
        SCHED0();

        // ---- P3: issue Af,Bf(ks0) from buf(t+1); stage (t+2).B0+B1;
        //          MFMA acc[4-7] += Ag*Bf2 (ks1)
#pragma unroll
        for (int m = 0; m < 4; ++m) Af[m] = FRAG(nabase, m * 16 + fr, fq);
#pragma unroll
        for (int n = 0; n < 4; ++n) Bf[n] = FRAG(nbbase, brB + n * 16 + fr, fq);
        stB(t + 2, 0, bufc + 32768);
        stB(t + 2, 1, bufc + 49152);
        SCHED0();
        __builtin_amdgcn_s_setprio(1);
#pragma unroll
        for (int m = 0; m < 4; ++m)
#pragma unroll
            for (int n = 0; n < 4; ++n)
                acc[4 + m][n] = __builtin_amdgcn_mfma_f32_16x16x32_bf16(Ag[m], Bf2[n], acc[4 + m][n], 0, 0, 0);
        __builtin_amdgcn_s_setprio(0);
        SCHED0(); BARS();
    }

    WAITV(0);   // drain clamped tail stages before epilogue
    BARS();

    // Epilogue: C/D layout col = lane&15, row = (lane>>4)*4 + reg (m89-verified).
    // Reduce s^2, s*xd, xd^2 over fr (shfl_xor); 1 atomicAdd/row/qty/wave.
#pragma unroll
    for (int m = 0; m < 8; ++m) {
#pragma unroll
        for (int jj = 0; jj < 4; ++jj) {
            const int row = brow + wr * 128 + m * 16 + fq * 4 + jj;
            const float* xp = xdot + (size_t)row * DTOT + bcol + wc * 64 + fr;
            float pns = 0.f, psx = 0.f, pxx = 0.f;
#pragma unroll
            for (int n = 0; n < 4; ++n) {
                float s  = acc[m][n][jj];
                float xv = xp[n * 16];
                pns += s * s; psx += s * xv; pxx += xv * xv;
            }
#pragma unroll
            for (int msk = 1; msk < 16; msk <<= 1) {
                pns += __shfl_xor(pns, msk);
                psx += __shfl_xor(psx, msk);
                pxx += __shfl_xor(pxx, msk);
            }
            if (fr == 0) {
                atomicAdd(&ns_acc[row], pns);
                atomicAdd(&sx_acc[row], psx);
                atomicAdd(&xx_acc[row], pxx);
            }
        }
    }
#undef FRAG
}

__global__ void finalize_k(const float* __restrict__ ns, const float* __restrict__ sx,
                           const float* __restrict__ xx, float* __restrict__ out) {
    int i = blockIdx.x * blockDim.x + threadIdx.x;
    if (i < MTOT) out[i] = xx[i] - (sx[i] * sx[i]) / (1.0f + ns[i]);
}

extern "C" void kernel_launch(void* const* d_in, const int* in_sizes, int n_in,
                              void* d_out, int out_size, void* d_ws, size_t ws_size,
                              hipStream_t stream) {
    const float* x  = (const float*)d_in[0];
    const float* xd = (const float*)d_in[1];
    const float* W  = (const float*)d_in[2];
    float* out = (float*)d_out;

    const size_t xbf_bytes = (size_t)MTOT * DTOT * 2;   // 67.1 MB
    const size_t wbf_bytes = (size_t)DTOT * DTOT * 2;   //  8.4 MB
    const size_t acc_bytes = (size_t)3 * MTOT * 4;      //  0.2 MB

    u16* xbf = (u16*)d_ws;
    u16* wbf = (u16*)((char*)d_ws + xbf_bytes);
    float* accs = (float*)((char*)d_ws + xbf_bytes + wbf_bytes);
    float* nsA = accs;
    float* sxA = accs + MTOT;
    float* xxA = accs + 2 * MTOT;
    (void)ws_size; (void)in_sizes; (void)n_in; (void)out_size;

    hipMemsetAsync(accs, 0, acc_bytes, stream);  // re-zero every call

    const int nx8 = MTOT * DTOT / 8, nw8 = DTOT * DTOT / 8;
    cast2_kernel<<<2048, 256, 0, stream>>>(x, W, xbf, wbf, nx8, nx8 + nw8);
    gemm8<<<512, 512, 0, stream>>>(xbf, wbf, xd, nsA, sxA, xxA);
    finalize_k<<<MTOT / 256, 256, 0, stream>>>(nsA, sxA, xxA, out);
}